// Round 8
// baseline (261.549 us; speedup 1.0000x reference)
//
#include <hip/hip_runtime.h>

typedef __attribute__((ext_vector_type(8))) short bf16x8;
typedef __attribute__((ext_vector_type(4))) float f32x4;
typedef __attribute__((ext_vector_type(2))) unsigned int u32x2;
typedef unsigned int u32;
typedef unsigned short u16;

constexpr int Bb = 4, S = 2048, D = 1024, H = 16, DK = 64, M = Bb * S;

#if __has_builtin(__builtin_amdgcn_exp2f)
#define EXP2F __builtin_amdgcn_exp2f
#else
#define EXP2F exp2f
#endif

__device__ __forceinline__ u16 f2bf(float f) {
  u32 u = __float_as_uint(f);
  return (u16)((u + 0x7fffu + ((u >> 16) & 1u)) >> 16);
}

__device__ __forceinline__ u32 cvt_pk_bf16(float a, float b) {
  u32 r;
  asm("v_cvt_pk_bf16_f32 %0, %1, %2" : "=v"(r) : "v"(a), "v"(b));
  return r;  // lo = bf16(a), hi = bf16(b), RNE
}

__device__ __forceinline__ void gld_lds16(const u16* g, u16* l) {
  __builtin_amdgcn_global_load_lds((const __attribute__((address_space(1))) u32*)g,
                                   (__attribute__((address_space(3))) u32*)l, 16, 0, 0);
}

// merged input cast: blocks [0,4096) -> 4 weights (1M elems each),
// blocks [4096,12288) -> x (8.39M elems). One launch instead of two.
struct CastAll { const float* s[5]; u16* d[5]; float sc[5]; };
__global__ __launch_bounds__(256) void cast_all_kernel(CastAll a) {
  int bid = blockIdx.x;
  int w, off;
  if (bid < 4096) { w = bid >> 10; off = ((bid & 1023) * 256 + threadIdx.x) * 4; }
  else            { w = 4;         off = ((bid - 4096) * 256 + threadIdx.x) * 4; }
  float sc = a.sc[w];
  float4 f = *(const float4*)(a.s[w] + off);
  ushort4 o;
  o.x = f2bf(f.x * sc); o.y = f2bf(f.y * sc); o.z = f2bf(f.z * sc); o.w = f2bf(f.w * sc);
  *(ushort4*)(a.d[w] + off) = o;
}

// ---- GEMM core: C[m,n] = sum_k A[m,k]*Bt[n,k], 128x128 tile, BK=64 ----
template <bool OUTF32>
__device__ __forceinline__ void gemm_core(const u16* __restrict__ A,
                                          const u16* __restrict__ Bt,
                                          float* __restrict__ Cf, u16* __restrict__ Cb,
                                          int Nn, int Kk, int m0, int n0,
                                          u16* As, u16* Bs) {
  const int tid = threadIdx.x, wave = tid >> 6, lane = tid & 63;
  const int quad = lane >> 4, col = lane & 15;
  const int wm = wave >> 1, wn = wave & 1;

  f32x4 acc[4][4];
#pragma unroll
  for (int i = 0; i < 4; i++)
#pragma unroll
    for (int j = 0; j < 4; j++) acc[i][j] = (f32x4){0.f, 0.f, 0.f, 0.f};

  for (int k0 = 0; k0 < Kk; k0 += 64) {
#pragma unroll
    for (int j = 0; j < 4; j++) {
      int g = (wave * 4 + j) * 64;
      int gl = g + lane;
      int r = gl >> 3, sl = gl & 7;
      int kof = (sl ^ (r & 7)) * 8;
      const u16* ga = A + (size_t)(m0 + r) * Kk + k0 + kof;
      gld_lds16(ga, &As[g * 8]);
      const u16* gb = Bt + (size_t)(n0 + r) * Kk + k0 + kof;
      gld_lds16(gb, &Bs[g * 8]);
    }
    __syncthreads();
#pragma unroll
    for (int kb = 0; kb < 2; kb++) {
      bf16x8 af[4], bfr[4];
#pragma unroll
      for (int mi = 0; mi < 4; mi++) {
        int R = wm * 64 + mi * 16 + col;
        af[mi] = *(const bf16x8*)&As[R * 64 + (((kb * 4 + quad) ^ (R & 7)) << 3)];
      }
#pragma unroll
      for (int ni = 0; ni < 4; ni++) {
        int R = wn * 64 + ni * 16 + col;
        bfr[ni] = *(const bf16x8*)&Bs[R * 64 + (((kb * 4 + quad) ^ (R & 7)) << 3)];
      }
#pragma unroll
      for (int mi = 0; mi < 4; mi++)
#pragma unroll
        for (int ni = 0; ni < 4; ni++)
          acc[mi][ni] = __builtin_amdgcn_mfma_f32_16x16x32_bf16(af[mi], bfr[ni], acc[mi][ni], 0, 0, 0);
    }
    __syncthreads();
  }
#pragma unroll
  for (int mi = 0; mi < 4; mi++)
#pragma unroll
    for (int ni = 0; ni < 4; ni++)
#pragma unroll
      for (int r = 0; r < 4; r++) {
        int row = m0 + wm * 64 + mi * 16 + quad * 4 + r;
        int cc = n0 + wn * 64 + ni * 16 + col;
        float v = acc[mi][ni][r];
        if (OUTF32) Cf[(size_t)row * Nn + cc] = v;
        else Cb[(size_t)row * Nn + cc] = f2bf(v);
      }
}

struct QkvArgs { const u16* bt[3]; u16* c[3]; };
__global__ __launch_bounds__(256) void gemm_qkv(const u16* __restrict__ A, QkvArgs q) {
  __shared__ __align__(16) u16 As[128 * 64];
  __shared__ __align__(16) u16 Bs[128 * 64];
  int sel = blockIdx.x >> 3;
  int n0 = (blockIdx.x & 7) * 128, m0 = blockIdx.y * 128;
  gemm_core<false>(A, q.bt[sel], nullptr, q.c[sel], D, D, m0, n0, As, Bs);
}

__global__ __launch_bounds__(256) void gemm_f32(const u16* __restrict__ A,
                                                const u16* __restrict__ Bt,
                                                float* __restrict__ C) {
  __shared__ __align__(16) u16 As[128 * 64];
  __shared__ __align__(16) u16 Bs[128 * 64];
  gemm_core<true>(A, Bt, C, nullptr, D, D, blockIdx.y * 128, blockIdx.x * 128, As, Bs);
}

// ---- flash attention, causal ----
// R7 structure (pair of 128-row q-blocks, uniform work, 512 blocks; swapped
// QK^T; P via cvt_pk -> swizzled Pw; ones-MFMA row sums; unroll-by-2 with
// compile-time buffer indices) + R8: KVBLK=128 -- two 64-key sub-tiles per
// barrier. Ks/Vt gain a key-half index (per-half layouts identical to R7,
// same conflict-free swizzles); Pw (16K) reused serially by the two halves
// (same-wave in-order DS). One __syncthreads + one DMA drain per 128 keys
// (was 2), and the two halves' QK/softmax/PV chains run barrier-free
// back-to-back => 2x independent work in flight per wave. LDS 80KB
// (Ks 32K + Vt 32K + Pw 16K) -> still 2 blocks/CU.
__global__ __launch_bounds__(256) void attn_kernel(const u16* __restrict__ Q,
                                                   const u16* __restrict__ K,
                                                   const u16* __restrict__ V,
                                                   u16* __restrict__ O) {
  __shared__ __align__(16) u16 Ks[2][2][2][64 * 32];  // [buf][key-half][d-half][key*32+slot]
  __shared__ __align__(16) u16 Vt[2][2][64 * 64];     // [buf][key-half] V^T [d][key-swz]
  __shared__ __align__(16) u16 Pw[4][32 * 64];        // per-wave P [q][key-swz] (per 64-key half)
  const int tid = threadIdx.x, wave = tid >> 6, lane = tid & 63;
  const int quad = lane >> 4, col = lane & 15;
  const int bh = blockIdx.x, b = bh >> 4, h = bh & 15;
  const int pair = blockIdx.y;  // 0..7
  const size_t base = (size_t)b * S * D + h * DK;

  const int vk0 = (tid & 31) * 2;  // V staging: keys (vk0, vk0+1) x 8 d's
  const int vdg = tid >> 5;        // d-group 0..7

  bf16x8 bones;
#pragma unroll
  for (int e = 0; e < 8; e++) bones[e] = (short)0x3F80;  // bf16 1.0

  // ---- hoisted lane-constant LDS addresses ----
  const int rsw = col & 7;
  const int ksl = ((quad ^ ((col >> 1) & 3)) & 3) << 3;
  const u16* kbase[2][2];
  const u16* vbase[2][2];
  u16* dk[2][2][2];
  u16* vwb[2][2];
#pragma unroll
  for (int bu = 0; bu < 2; bu++)
#pragma unroll
    for (int kh = 0; kh < 2; kh++) {
      kbase[bu][kh] = &Ks[bu][kh][0][col * 32 + ksl];
      vbase[bu][kh] = &Vt[bu][kh][col * 64];
      dk[bu][kh][0] = &Ks[bu][kh][0][wave * 64 * 8];
      dk[bu][kh][1] = &Ks[bu][kh][1][wave * 64 * 8];
      vwb[bu][kh] = &Vt[bu][kh][vdg * 8 * 64 + (vk0 & 7)];
    }
  const int vsl0 = ((quad ^ rsw) & 7) << 3;
  const int vsl1 = (((4 + quad) ^ rsw) & 7) << 3;
  u16* pww[2] = { &Pw[wave][col * 64 + (quad & 1) * 4],
                  &Pw[wave][(16 + col) * 64 + (quad & 1) * 4] };
  int swof[4];
#pragma unroll
  for (int n16 = 0; n16 < 4; n16++)
    swof[n16] = (((n16 * 2 + (quad >> 1)) ^ rsw) & 7) << 3;
  const u16* apbase[2] = { &Pw[wave][col * 64], &Pw[wave][(16 + col) * 64] };
  // K DMA lane mapping (source d-chunk pre-swizzled: chunk = slot ^ ((key>>1)&3))
  const int kk = tid >> 2;
  const int dch = (tid & 3) ^ ((kk >> 1) & 3);
  // V stage write offsets
  const int kgrp = vk0 >> 3;
  int vwof[8];
#pragma unroll
  for (int e = 0; e < 8; e++) vwof[e] = e * 64 + ((kgrp ^ e) & 7) * 8;

  auto vstage = [&](u16* wb, bf16x8 r0, bf16x8 r1) {
#pragma unroll
    for (int e = 0; e < 8; e++) {
      u32 val = ((u32)(u16)r0[e]) | ((u32)(u16)r1[e] << 16);
      *(u32*)(wb + vwof[e]) = val;
    }
  };

  for (int half = 0; half < 2; half++) {
    const int qb = half ? pair : 15 - pair;
    const int qw = qb * 128 + wave * 32;
    const int n128 = qb + 1;  // 128-key tiles

    bf16x8 aq[2][2];
#pragma unroll
    for (int mi = 0; mi < 2; mi++)
#pragma unroll
      for (int kb = 0; kb < 2; kb++)
        aq[mi][kb] = *(const bf16x8*)(Q + base + (size_t)(qw + mi * 16 + col) * D + kb * 32 + quad * 8);

    f32x4 ao[2][4], lacc[2];
#pragma unroll
    for (int mi = 0; mi < 2; mi++) {
      lacc[mi] = (f32x4){0.f, 0.f, 0.f, 0.f};
#pragma unroll
      for (int dg = 0; dg < 4; dg++) ao[mi][dg] = (f32x4){0.f, 0.f, 0.f, 0.f};
    }

    // compute body for one 64-key half; BF/HH compile-time per call site
    auto compute = [&](const int BF, const int HH, int kt) {
      const u16* kbK = kbase[BF][HH];
      bf16x8 bk0[4], bk1[4];
#pragma unroll
      for (int n16 = 0; n16 < 4; n16++) {
        bk0[n16] = *(const bf16x8*)(kbK + n16 * 512);
        bk1[n16] = *(const bf16x8*)(kbK + n16 * 512 + 2048);
      }
      f32x4 sacc[2][4];
#pragma unroll
      for (int qi = 0; qi < 2; qi++)
#pragma unroll
        for (int n16 = 0; n16 < 4; n16++) sacc[qi][n16] = (f32x4){0.f, 0.f, 0.f, 0.f};
      __builtin_amdgcn_s_setprio(1);
#pragma unroll
      for (int qi = 0; qi < 2; qi++)
#pragma unroll
        for (int n16 = 0; n16 < 4; n16++) {
          sacc[qi][n16] = __builtin_amdgcn_mfma_f32_16x16x32_bf16(bk0[n16], aq[qi][0], sacc[qi][n16], 0, 0, 0);
          sacc[qi][n16] = __builtin_amdgcn_mfma_f32_16x16x32_bf16(bk1[n16], aq[qi][1], sacc[qi][n16], 0, 0, 0);
        }
      __builtin_amdgcn_s_setprio(0);
      const bool full = (kt * 64 + 63) <= qw;  // wave-uniform: no masking
#pragma unroll
      for (int qi = 0; qi < 2; qi++) {
        const int qg = qw + qi * 16 + col;
#pragma unroll
        for (int n16 = 0; n16 < 4; n16++) {
          float p0 = EXP2F(sacc[qi][n16][0]);
          float p1 = EXP2F(sacc[qi][n16][1]);
          float p2 = EXP2F(sacc[qi][n16][2]);
          float p3 = EXP2F(sacc[qi][n16][3]);
          if (!full) {
            int kg = kt * 64 + n16 * 16 + quad * 4;
            p0 = (kg + 0 > qg) ? 0.f : p0;
            p1 = (kg + 1 > qg) ? 0.f : p1;
            p2 = (kg + 2 > qg) ? 0.f : p2;
            p3 = (kg + 3 > qg) ? 0.f : p3;
          }
          u32 lo = cvt_pk_bf16(p0, p1);
          u32 hi = cvt_pk_bf16(p2, p3);
          *(u32x2*)(pww[qi] + swof[n16]) = (u32x2){lo, hi};
        }
      }
      // PV + ones-MFMA row sums (same-wave LDS write->read, in-order DS)
      const u16* vtB = vbase[BF][HH];
      bf16x8 bv0[4], bv1[4];
#pragma unroll
      for (int dg = 0; dg < 4; dg++) {
        bv0[dg] = *(const bf16x8*)(vtB + dg * 1024 + vsl0);
        bv1[dg] = *(const bf16x8*)(vtB + dg * 1024 + vsl1);
      }
#pragma unroll
      for (int mi = 0; mi < 2; mi++) {
        bf16x8 ap0 = *(const bf16x8*)(apbase[mi] + vsl0);
        bf16x8 ap1 = *(const bf16x8*)(apbase[mi] + vsl1);
        __builtin_amdgcn_s_setprio(1);
#pragma unroll
        for (int dg = 0; dg < 4; dg++) {
          ao[mi][dg] = __builtin_amdgcn_mfma_f32_16x16x32_bf16(ap0, bv0[dg], ao[mi][dg], 0, 0, 0);
          ao[mi][dg] = __builtin_amdgcn_mfma_f32_16x16x32_bf16(ap1, bv1[dg], ao[mi][dg], 0, 0, 0);
        }
        lacc[mi] = __builtin_amdgcn_mfma_f32_16x16x32_bf16(ap0, bones, lacc[mi], 0, 0, 0);
        lacc[mi] = __builtin_amdgcn_mfma_f32_16x16x32_bf16(ap1, bones, lacc[mi], 0, 0, 0);
        __builtin_amdgcn_s_setprio(0);
      }
    };

    // ---- prologue ----
    bf16x8 vA0, vA1, vA2, vA3, vB0, vB1, vB2, vB3;
    const u16* gv = V + base + (size_t)vk0 * D + vdg * 8;  // tile 0
    vA0 = *(const bf16x8*)gv;                     // keys [0,64)
    vA1 = *(const bf16x8*)(gv + D);
    vA2 = *(const bf16x8*)(gv + (size_t)64 * D);  // keys [64,128)
    vA3 = *(const bf16x8*)(gv + (size_t)65 * D);
    __syncthreads();  // previous half's LDS readers done before restaging
    const u16* gk = K + base + (size_t)kk * D + dch * 8;   // tile 0
    gld_lds16(gk, dk[0][0][0]);
    gld_lds16(gk + 32, dk[0][0][1]);
    gld_lds16(gk + (size_t)64 * D, dk[0][1][0]);
    gld_lds16(gk + (size_t)64 * D + 32, dk[0][1][1]);
    gk += (size_t)128 * D;  // -> tile 1
    vstage(vwb[0][0], vA0, vA1);
    vstage(vwb[0][1], vA2, vA3);
    if (n128 > 1) {  // V tile 1 -> B regs
      vB0 = *(const bf16x8*)(gv + (size_t)128 * D);
      vB1 = *(const bf16x8*)(gv + (size_t)129 * D);
      vB2 = *(const bf16x8*)(gv + (size_t)192 * D);
      vB3 = *(const bf16x8*)(gv + (size_t)193 * D);
    }
    gv += (size_t)256 * D;  // -> tile 2

    // ---- main loop over 128-key tiles, unrolled by 2 (compile-time buf) ----
    for (int t2 = 0; t2 < n128; t2 += 2) {
      // body A: buf0
      __syncthreads();  // drains K(t2) DMA; publishes Vt[0][*]
      if (t2 + 1 < n128) {
        gld_lds16(gk, dk[1][0][0]);
        gld_lds16(gk + 32, dk[1][0][1]);
        gld_lds16(gk + (size_t)64 * D, dk[1][1][0]);
        gld_lds16(gk + (size_t)64 * D + 32, dk[1][1][1]);
        gk += (size_t)128 * D;
        vstage(vwb[1][0], vB0, vB1);
        vstage(vwb[1][1], vB2, vB3);
        if (t2 + 2 < n128) {
          vA0 = *(const bf16x8*)gv;
          vA1 = *(const bf16x8*)(gv + D);
          vA2 = *(const bf16x8*)(gv + (size_t)64 * D);
          vA3 = *(const bf16x8*)(gv + (size_t)65 * D);
          gv += (size_t)128 * D;
        }
      }
      compute(0, 0, 2 * t2);  // always active (t2 <= qb)
      if ((2 * t2 + 1) * 64 <= qw + 31) compute(0, 1, 2 * t2 + 1);
      if (t2 + 1 >= n128) break;
      // body B: buf1
      __syncthreads();  // drains K(t2+1) DMA; publishes Vt[1][*]
      if (t2 + 2 < n128) {
        gld_lds16(gk, dk[0][0][0]);
        gld_lds16(gk + 32, dk[0][0][1]);
        gld_lds16(gk + (size_t)64 * D, dk[0][1][0]);
        gld_lds16(gk + (size_t)64 * D + 32, dk[0][1][1]);
        gk += (size_t)128 * D;
        vstage(vwb[0][0], vA0, vA1);
        vstage(vwb[0][1], vA2, vA3);
        if (t2 + 3 < n128) {
          vB0 = *(const bf16x8*)gv;
          vB1 = *(const bf16x8*)(gv + D);
          vB2 = *(const bf16x8*)(gv + (size_t)64 * D);
          vB3 = *(const bf16x8*)(gv + (size_t)65 * D);
          gv += (size_t)128 * D;
        }
      }
      compute(1, 0, 2 * (t2 + 1));
      if ((2 * (t2 + 1) + 1) * 64 <= qw + 31) compute(1, 1, 2 * (t2 + 1) + 1);
    }
    // epilogue: normalize + write O
#pragma unroll
    for (int mi = 0; mi < 2; mi++)
#pragma unroll
      for (int r = 0; r < 4; r++) {
        float inv = 1.f / lacc[mi][r];
        int q = qw + mi * 16 + quad * 4 + r;
#pragma unroll
        for (int dg = 0; dg < 4; dg++)
          O[base + (size_t)q * D + dg * 16 + col] = f2bf(ao[mi][dg][r] * inv);
      }
  }
}

extern "C" void kernel_launch(void* const* d_in, const int* in_sizes, int n_in,
                              void* d_out, int out_size, void* d_ws, size_t ws_size,
                              hipStream_t stream) {
  const float* x  = (const float*)d_in[0];
  const float* Wq = (const float*)d_in[1];
  const float* Wk = (const float*)d_in[2];
  const float* Wv = (const float*)d_in[3];
  const float* Wo = (const float*)d_in[4];

  u16* xb  = (u16*)d_ws;
  u16* wqb = xb + (size_t)M * D;
  u16* wkb = wqb + (size_t)D * D;
  u16* wvb = wkb + (size_t)D * D;
  u16* wob = wvb + (size_t)D * D;
  u16* Qb  = wob + (size_t)D * D;
  u16* Kb  = Qb + (size_t)M * D;
  u16* Vb  = Kb + (size_t)M * D;
  u16* Ab  = xb;  // x dead after projections

  CastAll ca;
  ca.s[0] = Wq; ca.s[1] = Wk; ca.s[2] = Wv; ca.s[3] = Wo; ca.s[4] = x;
  ca.d[0] = wqb; ca.d[1] = wkb; ca.d[2] = wvb; ca.d[3] = wob; ca.d[4] = xb;
  ca.sc[0] = 0.18033688011112042f;  // 0.125 * log2(e) folded into Wq
  ca.sc[1] = 1.f; ca.sc[2] = 1.f; ca.sc[3] = 1.f; ca.sc[4] = 1.f;
  cast_all_kernel<<<4096 + M * D / 1024, 256, 0, stream>>>(ca);

  QkvArgs qa;
  qa.bt[0] = wqb; qa.bt[1] = wkb; qa.bt[2] = wvb;
  qa.c[0] = Qb; qa.c[1] = Kb; qa.c[2] = Vb;
  gemm_qkv<<<dim3(24, M / 128), 256, 0, stream>>>(xb, qa);

  attn_kernel<<<dim3(Bb * H, 8), 256, 0, stream>>>(Qb, Kb, Vb, Ab);

  gemm_f32<<<dim3(D / 128, M / 128), 256, 0, stream>>>(Ab, wob, (float*)d_out);
}

// Round 9
// 251.320 us; speedup vs baseline: 1.0407x; 1.0407x over previous
//
#include <hip/hip_runtime.h>

typedef __attribute__((ext_vector_type(8))) short bf16x8;
typedef __attribute__((ext_vector_type(4))) short bf16x4;
typedef __attribute__((ext_vector_type(4))) float f32x4;
typedef unsigned int u32;
typedef unsigned short u16;

constexpr int Bb = 4, S = 2048, D = 1024, H = 16, DK = 64, M = Bb * S;

#if __has_builtin(__builtin_amdgcn_exp2f)
#define EXP2F __builtin_amdgcn_exp2f
#else
#define EXP2F exp2f
#endif

__device__ __forceinline__ u16 f2bf(float f) {
  u32 u = __float_as_uint(f);
  return (u16)((u + 0x7fffu + ((u >> 16) & 1u)) >> 16);
}

__device__ __forceinline__ u32 cvt_pk_bf16(float a, float b) {
  u32 r;
  asm("v_cvt_pk_bf16_f32 %0, %1, %2" : "=v"(r) : "v"(a), "v"(b));
  return r;  // lo = bf16(a), hi = bf16(b), RNE
}

// K=16 bf16 MFMA (v4bf16 operands; _1k is the long-standing builtin name)
__device__ __forceinline__ f32x4 mfma16(bf16x4 a, bf16x4 b, f32x4 c) {
#if __has_builtin(__builtin_amdgcn_mfma_f32_16x16x16bf16_1k)
  return __builtin_amdgcn_mfma_f32_16x16x16bf16_1k(a, b, c, 0, 0, 0);
#else
  asm("v_mfma_f32_16x16x16_bf16 %0, %1, %2, %0" : "+v"(c) : "v"(a), "v"(b));
  return c;
#endif
}

__device__ __forceinline__ void gld_lds16(const u16* g, u16* l) {
  __builtin_amdgcn_global_load_lds((const __attribute__((address_space(1))) u32*)g,
                                   (__attribute__((address_space(3))) u32*)l, 16, 0, 0);
}

// merged input cast: blocks [0,4096) -> 4 weights (1M elems each),
// blocks [4096,12288) -> x (8.39M elems). One launch instead of two.
struct CastAll { const float* s[5]; u16* d[5]; float sc[5]; };
__global__ __launch_bounds__(256) void cast_all_kernel(CastAll a) {
  int bid = blockIdx.x;
  int w, off;
  if (bid < 4096) { w = bid >> 10; off = ((bid & 1023) * 256 + threadIdx.x) * 4; }
  else            { w = 4;         off = ((bid - 4096) * 256 + threadIdx.x) * 4; }
  float sc = a.sc[w];
  float4 f = *(const float4*)(a.s[w] + off);
  ushort4 o;
  o.x = f2bf(f.x * sc); o.y = f2bf(f.y * sc); o.z = f2bf(f.z * sc); o.w = f2bf(f.w * sc);
  *(ushort4*)(a.d[w] + off) = o;
}

// ---- GEMM core: C[m,n] = sum_k A[m,k]*Bt[n,k], 128x128 tile, BK=64 ----
template <bool OUTF32>
__device__ __forceinline__ void gemm_core(const u16* __restrict__ A,
                                          const u16* __restrict__ Bt,
                                          float* __restrict__ Cf, u16* __restrict__ Cb,
                                          int Nn, int Kk, int m0, int n0,
                                          u16* As, u16* Bs) {
  const int tid = threadIdx.x, wave = tid >> 6, lane = tid & 63;
  const int quad = lane >> 4, col = lane & 15;
  const int wm = wave >> 1, wn = wave & 1;

  f32x4 acc[4][4];
#pragma unroll
  for (int i = 0; i < 4; i++)
#pragma unroll
    for (int j = 0; j < 4; j++) acc[i][j] = (f32x4){0.f, 0.f, 0.f, 0.f};

  for (int k0 = 0; k0 < Kk; k0 += 64) {
#pragma unroll
    for (int j = 0; j < 4; j++) {
      int g = (wave * 4 + j) * 64;
      int gl = g + lane;
      int r = gl >> 3, sl = gl & 7;
      int kof = (sl ^ (r & 7)) * 8;
      const u16* ga = A + (size_t)(m0 + r) * Kk + k0 + kof;
      gld_lds16(ga, &As[g * 8]);
      const u16* gb = Bt + (size_t)(n0 + r) * Kk + k0 + kof;
      gld_lds16(gb, &Bs[g * 8]);
    }
    __syncthreads();
#pragma unroll
    for (int kb = 0; kb < 2; kb++) {
      bf16x8 af[4], bfr[4];
#pragma unroll
      for (int mi = 0; mi < 4; mi++) {
        int R = wm * 64 + mi * 16 + col;
        af[mi] = *(const bf16x8*)&As[R * 64 + (((kb * 4 + quad) ^ (R & 7)) << 3)];
      }
#pragma unroll
      for (int ni = 0; ni < 4; ni++) {
        int R = wn * 64 + ni * 16 + col;
        bfr[ni] = *(const bf16x8*)&Bs[R * 64 + (((kb * 4 + quad) ^ (R & 7)) << 3)];
      }
#pragma unroll
      for (int mi = 0; mi < 4; mi++)
#pragma unroll
        for (int ni = 0; ni < 4; ni++)
          acc[mi][ni] = __builtin_amdgcn_mfma_f32_16x16x32_bf16(af[mi], bfr[ni], acc[mi][ni], 0, 0, 0);
    }
    __syncthreads();
  }
#pragma unroll
  for (int mi = 0; mi < 4; mi++)
#pragma unroll
    for (int ni = 0; ni < 4; ni++)
#pragma unroll
      for (int r = 0; r < 4; r++) {
        int row = m0 + wm * 64 + mi * 16 + quad * 4 + r;
        int cc = n0 + wn * 64 + ni * 16 + col;
        float v = acc[mi][ni][r];
        if (OUTF32) Cf[(size_t)row * Nn + cc] = v;
        else Cb[(size_t)row * Nn + cc] = f2bf(v);
      }
}

struct QkvArgs { const u16* bt[3]; u16* c[3]; };
__global__ __launch_bounds__(256) void gemm_qkv(const u16* __restrict__ A, QkvArgs q) {
  __shared__ __align__(16) u16 As[128 * 64];
  __shared__ __align__(16) u16 Bs[128 * 64];
  int sel = blockIdx.x >> 3;
  int n0 = (blockIdx.x & 7) * 128, m0 = blockIdx.y * 128;
  gemm_core<false>(A, q.bt[sel], nullptr, q.c[sel], D, D, m0, n0, As, Bs);
}

__global__ __launch_bounds__(256) void gemm_f32(const u16* __restrict__ A,
                                                const u16* __restrict__ Bt,
                                                float* __restrict__ C) {
  __shared__ __align__(16) u16 As[128 * 64];
  __shared__ __align__(16) u16 Bs[128 * 64];
  gemm_core<true>(A, Bt, C, nullptr, D, D, blockIdx.y * 128, blockIdx.x * 128, As, Bs);
}

// ---- flash attention, causal ----
// R7 structure (best: pair of 128-row q-blocks (15-p,p) => uniform 36
// k-iters, 512 blocks; K double-buffered via global_load_lds DMA with
// pre-swizzled source; V double-buffered regs->LDS transposed; swapped
// QK^T (mfma(K,Q)); unroll-by-2 with compile-time buffer indices; hoisted
// lane-constant addresses) + R9: IN-REGISTER K16 PV (from R5, correctness
// harness-verified there). The swapped-QK^T C-layout (lane holds
// P[key=16*n16+4*quad+r][q=16*qi+col]) IS the K=16 MFMA A-fragment layout
// [row=col][k=quad*4+e], so {cvt_pk(p0,p1),cvt_pk(p2,p3)} feeds PV
// directly: the P LDS round-trip (8KB/wave/iter of the ~28KB total) is
// gone. Rationale: attn is LDS-pipe-bound (~224KB/iter/CU vs 128B/cyc
// => ~1750cyc of the 2450cyc wall); -29% LDS traffic. MFMA issue rises
// (40 K16 vs 20 K32) but matrix pipe has headroom. LDS 32KB, no Pw.
__global__ __launch_bounds__(256) void attn_kernel(const u16* __restrict__ Q,
                                                   const u16* __restrict__ K,
                                                   const u16* __restrict__ V,
                                                   u16* __restrict__ O) {
  __shared__ __align__(16) u16 Ks[2][2][64 * 32];  // [buf][d-half][key*32 + swz-slot]
  __shared__ __align__(16) u16 Vt[2][64 * 64];     // [buf] V^T [d][key-swizzled]
  const int tid = threadIdx.x, wave = tid >> 6, lane = tid & 63;
  const int quad = lane >> 4, col = lane & 15;
  const int bh = blockIdx.x, b = bh >> 4, h = bh & 15;
  const int pair = blockIdx.y;  // 0..7
  const size_t base = (size_t)b * S * D + h * DK;

  const int vk0 = (tid & 31) * 2;  // V staging: keys (vk0, vk0+1) x 8 d's
  const int vdg = tid >> 5;        // d-group 0..7

  bf16x4 bones4;
#pragma unroll
  for (int e = 0; e < 4; e++) bones4[e] = (short)0x3F80;  // bf16 1.0

  // ---- hoisted lane-constant LDS addresses ----
  const int rsw = col & 7;
  const int ksl = ((quad ^ ((col >> 1) & 3)) & 3) << 3;
  const u16* kbase[2] = { &Ks[0][0][col * 32 + ksl], &Ks[1][0][col * 32 + ksl] };
  // K16 PV: bv[dg] at Vt[buf][(dg*16+col)*64 + slof[n16] + (quad&1)*4]
  const u16* vbase16[2] = { &Vt[0][col * 64 + ((quad & 1) << 2)],
                            &Vt[1][col * 64 + ((quad & 1) << 2)] };
  int slof[4];
#pragma unroll
  for (int n16 = 0; n16 < 4; n16++)
    slof[n16] = (((2 * n16 + (quad >> 1)) ^ rsw) & 7) << 3;
  // K DMA lane mapping (source d-chunk pre-swizzled: chunk = slot ^ ((key>>1)&3))
  const int kk = tid >> 2;
  const int dch = (tid & 3) ^ ((kk >> 1) & 3);
  const int cb = wave * 64;
  u16* dk[2][2] = { { &Ks[0][0][cb * 8], &Ks[0][1][cb * 8] },
                    { &Ks[1][0][cb * 8], &Ks[1][1][cb * 8] } };
  // V stage write addressing
  const int kgrp = vk0 >> 3, kin = vk0 & 7;
  u16* vwb[2] = { &Vt[0][vdg * 8 * 64 + kin], &Vt[1][vdg * 8 * 64 + kin] };
  int vwof[8];
#pragma unroll
  for (int e = 0; e < 8; e++) vwof[e] = e * 64 + ((kgrp ^ e) & 7) * 8;

  auto vstage = [&](const int buf, bf16x8 r0, bf16x8 r1) {
    u16* wb = vwb[buf];
#pragma unroll
    for (int e = 0; e < 8; e++) {
      u32 val = ((u32)(u16)r0[e]) | ((u32)(u16)r1[e] << 16);
      *(u32*)(wb + vwof[e]) = val;
    }
  };

  for (int half = 0; half < 2; half++) {
    const int qb = half ? pair : 15 - pair;
    const int qw = qb * 128 + wave * 32;
    const int nkt = 2 * qb + 2;  // even

    bf16x8 aq[2][2];
#pragma unroll
    for (int mi = 0; mi < 2; mi++)
#pragma unroll
      for (int kb = 0; kb < 2; kb++)
        aq[mi][kb] = *(const bf16x8*)(Q + base + (size_t)(qw + mi * 16 + col) * D + kb * 32 + quad * 8);

    f32x4 ao[2][4], lacc[2];
#pragma unroll
    for (int mi = 0; mi < 2; mi++) {
      lacc[mi] = (f32x4){0.f, 0.f, 0.f, 0.f};
#pragma unroll
      for (int dg = 0; dg < 4; dg++) ao[mi][dg] = (f32x4){0.f, 0.f, 0.f, 0.f};
    }

    // compute body for one k-tile; BF is compile-time per unrolled body
    auto compute = [&](const int BF, int kt) {
      const u16* kbK = kbase[BF];
      bf16x8 bk0[4], bk1[4];
#pragma unroll
      for (int n16 = 0; n16 < 4; n16++) {
        bk0[n16] = *(const bf16x8*)(kbK + n16 * 512);
        bk1[n16] = *(const bf16x8*)(kbK + n16 * 512 + 2048);
      }
      f32x4 sacc[2][4];
#pragma unroll
      for (int qi = 0; qi < 2; qi++)
#pragma unroll
        for (int n16 = 0; n16 < 4; n16++) sacc[qi][n16] = (f32x4){0.f, 0.f, 0.f, 0.f};
      __builtin_amdgcn_s_setprio(1);
#pragma unroll
      for (int qi = 0; qi < 2; qi++)
#pragma unroll
        for (int n16 = 0; n16 < 4; n16++) {
          sacc[qi][n16] = __builtin_amdgcn_mfma_f32_16x16x32_bf16(bk0[n16], aq[qi][0], sacc[qi][n16], 0, 0, 0);
          sacc[qi][n16] = __builtin_amdgcn_mfma_f32_16x16x32_bf16(bk1[n16], aq[qi][1], sacc[qi][n16], 0, 0, 0);
        }
      __builtin_amdgcn_s_setprio(0);
      const bool full = (kt * 64 + 63) <= qw;  // wave-uniform: no masking
      // p = exp2(s); lane holds keys 16*n16+4*quad+{0..3} for q = 16*qi+col
      // == the K16 A-fragment A[row=col][k=quad*4+e]: pack in-register.
      bf16x4 ap[2][4];
#pragma unroll
      for (int qi = 0; qi < 2; qi++) {
        const int qg = qw + qi * 16 + col;
#pragma unroll
        for (int n16 = 0; n16 < 4; n16++) {
          float p0 = EXP2F(sacc[qi][n16][0]);
          float p1 = EXP2F(sacc[qi][n16][1]);
          float p2 = EXP2F(sacc[qi][n16][2]);
          float p3 = EXP2F(sacc[qi][n16][3]);
          if (!full) {
            int kg = kt * 64 + n16 * 16 + quad * 4;
            p0 = (kg + 0 > qg) ? 0.f : p0;
            p1 = (kg + 1 > qg) ? 0.f : p1;
            p2 = (kg + 2 > qg) ? 0.f : p2;
            p3 = (kg + 3 > qg) ? 0.f : p3;
          }
          union { u32 u[2]; bf16x4 v; } pk;
          pk.u[0] = cvt_pk_bf16(p0, p1);
          pk.u[1] = cvt_pk_bf16(p2, p3);
          ap[qi][n16] = pk.v;
        }
      }
      // PV (K=16) + ones-MFMA row sums; V B-frags: 4-key ds_read_b64 from
      // Vt (keys n16*16+quad*4+{0..3} at d=dg*16+col) -- layout verified R5.
      const u16* vtB = vbase16[BF];
#pragma unroll
      for (int n16 = 0; n16 < 4; n16++) {
        bf16x4 bv[4];
#pragma unroll
        for (int dg = 0; dg < 4; dg++)
          bv[dg] = *(const bf16x4*)(vtB + dg * 1024 + slof[n16]);
        __builtin_amdgcn_s_setprio(1);
#pragma unroll
        for (int mi = 0; mi < 2; mi++) {
#pragma unroll
          for (int dg = 0; dg < 4; dg++)
            ao[mi][dg] = mfma16(ap[mi][n16], bv[dg], ao[mi][dg]);
          lacc[mi] = mfma16(ap[mi][n16], bones4, lacc[mi]);
        }
        __builtin_amdgcn_s_setprio(0);
      }
    };

    // ---- prologue ----
    bf16x8 vA0, vA1, vB0, vB1;
    const u16* gv = V + base + (size_t)vk0 * D + vdg * 8;  // V tile 0
    vA0 = *(const bf16x8*)gv;
    vA1 = *(const bf16x8*)(gv + D);
    __syncthreads();  // previous half's LDS readers done before restaging
    const u16* gk = K + base + (size_t)kk * D + dch * 8;   // K tile 0
    gld_lds16(gk, dk[0][0]);
    gld_lds16(gk + 32, dk[0][1]);
    gk += (size_t)64 * D;  // -> tile 1
    vstage(0, vA0, vA1);
    vB0 = *(const bf16x8*)(gv + (size_t)64 * D);           // V tile 1
    vB1 = *(const bf16x8*)(gv + (size_t)64 * D + D);
    gv += (size_t)128 * D;  // -> tile 2

    // ---- main loop, unrolled by 2 (bf = 0 then 1, compile-time) ----
    for (int kt = 0; kt < nkt; kt += 2) {
      // even body: bf=0, stage tile kt+1 -> buf1 from vB, load vA = tile kt+2
      __syncthreads();  // drains K(kt) DMA; publishes Vt[0]
      {
        // kt+1 < nkt always (nkt even)
        gld_lds16(gk, dk[1][0]);
        gld_lds16(gk + 32, dk[1][1]);
        gk += (size_t)64 * D;
        vstage(1, vB0, vB1);
        if (kt + 2 < nkt) {
          vA0 = *(const bf16x8*)gv;
          vA1 = *(const bf16x8*)(gv + D);
          gv += (size_t)64 * D;
        }
        if (kt * 64 <= qw + 31) compute(0, kt);
      }
      // odd body: bf=1, stage tile kt+2 -> buf0 from vA, load vB = tile kt+3
      __syncthreads();  // drains K(kt+1) DMA; publishes Vt[1]
      {
        const int kt1 = kt + 1;
        if (kt1 + 1 < nkt) {
          gld_lds16(gk, dk[0][0]);
          gld_lds16(gk + 32, dk[0][1]);
          gk += (size_t)64 * D;
          vstage(0, vA0, vA1);
          if (kt1 + 2 < nkt) {
            vB0 = *(const bf16x8*)gv;
            vB1 = *(const bf16x8*)(gv + D);
            gv += (size_t)64 * D;
          }
        }
        if (kt1 * 64 <= qw + 31) compute(1, kt1);
      }
    }
    // epilogue: normalize + write O
#pragma unroll
    for (int mi = 0; mi < 2; mi++)
#pragma unroll
      for (int r = 0; r < 4; r++) {
        float inv = 1.f / lacc[mi][r];
        int q = qw + mi * 16 + quad * 4 + r;
#pragma unroll
        for (int dg = 0; dg < 4; dg++)
          O[base + (size_t)q * D + dg * 16 + col] = f2bf(ao[mi][dg][r] * inv);
      }
  }
}

extern "C" void kernel_launch(void* const* d_in, const int* in_sizes, int n_in,
                              void* d_out, int out_size, void* d_ws, size_t ws_size,
                              hipStream_t stream) {
  const float* x  = (const float*)d_in[0];
  const float* Wq = (const float*)d_in[1];
  const float* Wk = (const float*)d_in[2];
  const float* Wv = (const float*)d_in[3];
  const float* Wo = (const float*)d_in[4];

  u16* xb  = (u16*)d_ws;
  u16* wqb = xb + (size_t)M * D;
  u16* wkb = wqb + (size_t)D * D;
  u16* wvb = wkb + (size_t)D * D;
  u16* wob = wvb + (size_t)D * D;
  u16* Qb  = wob + (size_t)D * D;
  u16* Kb  = Qb + (size_t)M * D;
  u16* Vb  = Kb + (size_t)M * D;
  u16* Ab  = xb;  // x dead after projections

  CastAll ca;
  ca.s[0] = Wq; ca.s[1] = Wk; ca.s[2] = Wv; ca.s[3] = Wo; ca.s[4] = x;
  ca.d[0] = wqb; ca.d[1] = wkb; ca.d[2] = wvb; ca.d[3] = wob; ca.d[4] = xb;
  ca.sc[0] = 0.18033688011112042f;  // 0.125 * log2(e) folded into Wq
  ca.sc[1] = 1.f; ca.sc[2] = 1.f; ca.sc[3] = 1.f; ca.sc[4] = 1.f;
  cast_all_kernel<<<4096 + M * D / 1024, 256, 0, stream>>>(ca);

  QkvArgs qa;
  qa.bt[0] = wqb; qa.bt[1] = wkb; qa.bt[2] = wvb;
  qa.c[0] = Qb; qa.c[1] = Kb; qa.c[2] = Vb;
  gemm_qkv<<<dim3(24, M / 128), 256, 0, stream>>>(xb, qa);

  attn_kernel<<<dim3(Bb * H, 8), 256, 0, stream>>>(Qb, Kb, Vb, Ab);

  gemm_f32<<<dim3(D / 128, M / 128), 256, 0, stream>>>(Ab, wob, (float*)d_out);
}

// Round 10
// 248.629 us; speedup vs baseline: 1.0520x; 1.0108x over previous
//
#include <hip/hip_runtime.h>

typedef __attribute__((ext_vector_type(8))) short bf16x8;
typedef __attribute__((ext_vector_type(4))) float f32x4;
typedef __attribute__((ext_vector_type(2))) unsigned int u32x2;
typedef unsigned int u32;
typedef unsigned short u16;

constexpr int Bb = 4, S = 2048, D = 1024, H = 16, DK = 64, M = Bb * S;

#if __has_builtin(__builtin_amdgcn_exp2f)
#define EXP2F __builtin_amdgcn_exp2f
#else
#define EXP2F exp2f
#endif

__device__ __forceinline__ u16 f2bf(float f) {
  u32 u = __float_as_uint(f);
  return (u16)((u + 0x7fffu + ((u >> 16) & 1u)) >> 16);
}

__device__ __forceinline__ u32 cvt_pk_bf16(float a, float b) {
  u32 r;
  asm("v_cvt_pk_bf16_f32 %0, %1, %2" : "=v"(r) : "v"(a), "v"(b));
  return r;  // lo = bf16(a), hi = bf16(b), RNE
}

__device__ __forceinline__ void gld_lds16(const u16* g, u16* l) {
  __builtin_amdgcn_global_load_lds((const __attribute__((address_space(1))) u32*)g,
                                   (__attribute__((address_space(3))) u32*)l, 16, 0, 0);
}

// merged input cast: blocks [0,4096) -> 4 weights (1M elems each),
// blocks [4096,12288) -> x (8.39M elems).
struct CastAll { const float* s[5]; u16* d[5]; float sc[5]; };
__global__ __launch_bounds__(256) void cast_all_kernel(CastAll a) {
  int bid = blockIdx.x;
  int w, off;
  if (bid < 4096) { w = bid >> 10; off = ((bid & 1023) * 256 + threadIdx.x) * 4; }
  else            { w = 4;         off = ((bid - 4096) * 256 + threadIdx.x) * 4; }
  float sc = a.sc[w];
  float4 f = *(const float4*)(a.s[w] + off);
  ushort4 o;
  o.x = f2bf(f.x * sc); o.y = f2bf(f.y * sc); o.z = f2bf(f.z * sc); o.w = f2bf(f.w * sc);
  *(ushort4*)(a.d[w] + off) = o;
}

// ---- GEMM: C[m,n] = sum_k A[m,k]*Bt[n,k]; 256x128 tile, BK=64, K=1024.
// 512 threads = 8 waves (4 M x 2 N), per-wave 64x64 out (acc[4][4]).
// Double-buffered LDS (A 2x32KB + B 2x16KB = 96KB). Counted-vmcnt pipeline
// (T4): raw s_barrier + "s_waitcnt vmcnt(6)" -- the 6 global_load_lds of
// K-step t+1 stay IN FLIGHT across the barriers while K-step t computes;
// vmcnt(6) drains exactly the 6 older loads of step t. Tail peels to
// vmcnt(0). Per K-step: barrier1 (all waves done reading buf nb) -> stage
// t+1 -> nb -> vmcnt(6) -> barrier2 (step-t data landed for ALL waves,
// since each wave vmcnt-waited its own DMA before arriving) -> reads+MFMA.
// Wave reaches barrier1 only after its MFMAs consumed all ds_reads (the
// compiler's lgkmcnt waits precede the last MFMA), so buf nb is re-writable.
template <bool OUTF32>
__device__ __forceinline__ void gemm_body(const u16* __restrict__ A,
                                          const u16* __restrict__ Bt,
                                          float* __restrict__ Cf, u16* __restrict__ Cb,
                                          int m0, int n0, u16* As0, u16* As1,
                                          u16* Bs0, u16* Bs1) {
  constexpr int K = 1024;
  const int tid = threadIdx.x, wave = tid >> 6, lane = tid & 63;
  const int quad = lane >> 4, col = lane & 15;
  const int wm = wave >> 1, wn = wave & 1;

  // per-thread staging source pointers (advance +64 per K-step) and
  // lane-constant LDS destinations for both buffers
  const u16* pA[4];
  u16* dA0[4]; u16* dA1[4];
#pragma unroll
  for (int j = 0; j < 4; j++) {
    int gl = tid + j * 512;
    int r = gl >> 3, sl = gl & 7;
    int kof = (sl ^ (r & 7)) * 8;
    pA[j] = A + (size_t)(m0 + r) * K + kof;
    dA0[j] = As0 + gl * 8; dA1[j] = As1 + gl * 8;
  }
  const u16* pB[2];
  u16* dB0[2]; u16* dB1[2];
#pragma unroll
  for (int j = 0; j < 2; j++) {
    int gl = tid + j * 512;
    int r = gl >> 3, sl = gl & 7;
    int kof = (sl ^ (r & 7)) * 8;
    pB[j] = Bt + (size_t)(n0 + r) * K + kof;
    dB0[j] = Bs0 + gl * 8; dB1[j] = Bs1 + gl * 8;
  }
  // hoisted lane-constant read bases
  const u16* rdA0[4]; const u16* rdA1[4];
  const u16* rdB0[4]; const u16* rdB1[4];
#pragma unroll
  for (int mi = 0; mi < 4; mi++) {
    int R = wm * 64 + mi * 16 + col;
    rdA0[mi] = As0 + R * 64 + ((quad ^ (R & 7)) << 3);  // kb=0; kb=1 adds (4^0..) via offset below
    rdA1[mi] = As1 + R * 64 + ((quad ^ (R & 7)) << 3);
  }
#pragma unroll
  for (int ni = 0; ni < 4; ni++) {
    int R = wn * 64 + ni * 16 + col;
    rdB0[ni] = Bs0 + R * 64 + ((quad ^ (R & 7)) << 3);
    rdB1[ni] = Bs1 + R * 64 + ((quad ^ (R & 7)) << 3);
  }
  // kb=1 read offset: chunk (4+quad)^(R&7) vs quad^(R&7): XOR with 4 flips bit2
  // of the chunk index -> byte offset difference = ((quad^4)^(R&7))*8 - ... use
  // direct: delta = (((4 + quad) ^ (R & 7)) - (quad ^ (R & 7))) * 8; since bit2
  // of quad is 0 (quad<4), (4+quad)^x = (quad^x)+4 or ... (4|quad)^x: bit2 of x
  // (R&7) can be 0/1: if 0 -> +4 chunks; if 1 -> -4 chunks. Lane-constant per R.
  int dkbA[4], dkbB[4];
#pragma unroll
  for (int mi = 0; mi < 4; mi++) {
    int R = wm * 64 + mi * 16 + col;
    dkbA[mi] = ((((4 + quad) ^ (R & 7)) - (quad ^ (R & 7))) << 3);
  }
#pragma unroll
  for (int ni = 0; ni < 4; ni++) {
    int R = wn * 64 + ni * 16 + col;
    dkbB[ni] = ((((4 + quad) ^ (R & 7)) - (quad ^ (R & 7))) << 3);
  }

  f32x4 acc[4][4];
#pragma unroll
  for (int i = 0; i < 4; i++)
#pragma unroll
    for (int j = 0; j < 4; j++) acc[i][j] = (f32x4){0.f, 0.f, 0.f, 0.f};

  auto stage = [&](u16* const* dA, u16* const* dB) {
#pragma unroll
    for (int j = 0; j < 4; j++) gld_lds16(pA[j], dA[j]);
#pragma unroll
    for (int j = 0; j < 2; j++) gld_lds16(pB[j], dB[j]);
#pragma unroll
    for (int j = 0; j < 4; j++) pA[j] += 64;
#pragma unroll
    for (int j = 0; j < 2; j++) pB[j] += 64;
  };

  auto compute = [&](const u16* const* rdA, const u16* const* rdB) {
    bf16x8 af[4][2], bfr[4][2];
#pragma unroll
    for (int mi = 0; mi < 4; mi++) {
      af[mi][0] = *(const bf16x8*)(rdA[mi]);
      af[mi][1] = *(const bf16x8*)(rdA[mi] + dkbA[mi]);
    }
#pragma unroll
    for (int ni = 0; ni < 4; ni++) {
      bfr[ni][0] = *(const bf16x8*)(rdB[ni]);
      bfr[ni][1] = *(const bf16x8*)(rdB[ni] + dkbB[ni]);
    }
#pragma unroll
    for (int kb = 0; kb < 2; kb++)
#pragma unroll
      for (int mi = 0; mi < 4; mi++)
#pragma unroll
        for (int ni = 0; ni < 4; ni++)
          acc[mi][ni] = __builtin_amdgcn_mfma_f32_16x16x32_bf16(af[mi][kb], bfr[ni][kb], acc[mi][ni], 0, 0, 0);
  };

  // prologue: K-step 0 -> buf0
  stage(dA0, dB0);

  // 16 K-steps, unrolled x2 (compile-time buffers); last body peels vmcnt(0)
#pragma unroll 1
  for (int t2 = 0; t2 < 8; t2++) {
    // body A: compute step 2*t2 from buf0; stage 2*t2+1 -> buf1 (always valid)
    __builtin_amdgcn_sched_barrier(0);
    __builtin_amdgcn_s_barrier();  // all waves done reading buf1
    __builtin_amdgcn_sched_barrier(0);
    stage(dA1, dB1);
    asm volatile("s_waitcnt vmcnt(6)" ::: "memory");  // step-2*t2 loads landed
    __builtin_amdgcn_sched_barrier(0);
    __builtin_amdgcn_s_barrier();  // ...for every wave
    __builtin_amdgcn_sched_barrier(0);
    compute(rdA0, rdB0);
    // body B: compute step 2*t2+1 from buf1; stage 2*t2+2 -> buf0 unless done
    __builtin_amdgcn_sched_barrier(0);
    __builtin_amdgcn_s_barrier();  // all waves done reading buf0
    __builtin_amdgcn_sched_barrier(0);
    if (t2 < 7) {
      stage(dA0, dB0);
      asm volatile("s_waitcnt vmcnt(6)" ::: "memory");
    } else {
      asm volatile("s_waitcnt vmcnt(0)" ::: "memory");
    }
    __builtin_amdgcn_sched_barrier(0);
    __builtin_amdgcn_s_barrier();
    __builtin_amdgcn_sched_barrier(0);
    compute(rdA1, rdB1);
  }

  // epilogue
#pragma unroll
  for (int mi = 0; mi < 4; mi++)
#pragma unroll
    for (int ni = 0; ni < 4; ni++)
#pragma unroll
      for (int r = 0; r < 4; r++) {
        int row = m0 + wm * 64 + mi * 16 + quad * 4 + r;
        int cc = n0 + wn * 64 + ni * 16 + col;
        float v = acc[mi][ni][r];
        if (OUTF32) Cf[(size_t)row * D + cc] = v;
        else Cb[(size_t)row * D + cc] = f2bf(v);
      }
}

struct QkvArgs { const u16* bt[3]; u16* c[3]; };
__global__ __launch_bounds__(512) void gemm_qkv(const u16* __restrict__ A, QkvArgs q) {
  __shared__ __align__(16) u16 As[2][256 * 64];
  __shared__ __align__(16) u16 Bs[2][128 * 64];
  int sel = blockIdx.x >> 3;
  int n0 = (blockIdx.x & 7) * 128, m0 = blockIdx.y * 256;
  gemm_body<false>(A, q.bt[sel], nullptr, q.c[sel], m0, n0, As[0], As[1], Bs[0], Bs[1]);
}

__global__ __launch_bounds__(512) void gemm_f32(const u16* __restrict__ A,
                                                const u16* __restrict__ Bt,
                                                float* __restrict__ C) {
  __shared__ __align__(16) u16 As[2][256 * 64];
  __shared__ __align__(16) u16 Bs[2][128 * 64];
  gemm_body<true>(A, Bt, C, nullptr, blockIdx.y * 256, blockIdx.x * 128, As[0], As[1], Bs[0], Bs[1]);
}

// ---- flash attention, causal ---- (exact R7 structure: best verified 69.4us)
__global__ __launch_bounds__(256) void attn_kernel(const u16* __restrict__ Q,
                                                   const u16* __restrict__ K,
                                                   const u16* __restrict__ V,
                                                   u16* __restrict__ O) {
  __shared__ __align__(16) u16 Ks[2][2][64 * 32];  // [buf][d-half][key*32 + swz-slot]
  __shared__ __align__(16) u16 Vt[2][64 * 64];     // [buf] V^T [d][key-swizzled]
  __shared__ __align__(16) u16 Pw[4][32 * 64];     // per-wave P [q][key-swizzled]
  const int tid = threadIdx.x, wave = tid >> 6, lane = tid & 63;
  const int quad = lane >> 4, col = lane & 15;
  const int bh = blockIdx.x, b = bh >> 4, h = bh & 15;
  const int pair = blockIdx.y;  // 0..7
  const size_t base = (size_t)b * S * D + h * DK;

  const int vk0 = (tid & 31) * 2;  // V staging: keys (vk0, vk0+1) x 8 d's
  const int vdg = tid >> 5;        // d-group 0..7

  bf16x8 bones;
#pragma unroll
  for (int e = 0; e < 8; e++) bones[e] = (short)0x3F80;  // bf16 1.0

  // ---- hoisted lane-constant LDS addresses ----
  const int rsw = col & 7;
  const int ksl = ((quad ^ ((col >> 1) & 3)) & 3) << 3;
  const u16* kbase[2] = { &Ks[0][0][col * 32 + ksl], &Ks[1][0][col * 32 + ksl] };
  const int vsl0 = ((quad ^ rsw) & 7) << 3;          // slot offsets (elements)
  const int vsl1 = (((4 + quad) ^ rsw) & 7) << 3;
  const u16* vbase[2] = { &Vt[0][col * 64], &Vt[1][col * 64] };
  u16* pww[2] = { &Pw[wave][col * 64 + (quad & 1) * 4],
                  &Pw[wave][(16 + col) * 64 + (quad & 1) * 4] };
  int swof[4];
#pragma unroll
  for (int n16 = 0; n16 < 4; n16++)
    swof[n16] = (((n16 * 2 + (quad >> 1)) ^ rsw) & 7) << 3;
  const u16* apbase[2] = { &Pw[wave][col * 64], &Pw[wave][(16 + col) * 64] };
  // K DMA lane mapping (source d-chunk pre-swizzled: chunk = slot ^ ((key>>1)&3))
  const int kk = tid >> 2;
  const int dch = (tid & 3) ^ ((kk >> 1) & 3);
  const int cb = wave * 64;
  u16* dk[2][2] = { { &Ks[0][0][cb * 8], &Ks[0][1][cb * 8] },
                    { &Ks[1][0][cb * 8], &Ks[1][1][cb * 8] } };
  // V stage write addressing
  const int kgrp = vk0 >> 3, kin = vk0 & 7;
  u16* vwb[2] = { &Vt[0][vdg * 8 * 64 + kin], &Vt[1][vdg * 8 * 64 + kin] };
  int vwof[8];
#pragma unroll
  for (int e = 0; e < 8; e++) vwof[e] = e * 64 + ((kgrp ^ e) & 7) * 8;

  auto vstage = [&](const int buf, bf16x8 r0, bf16x8 r1) {
    u16* wb = vwb[buf];
#pragma unroll
    for (int e = 0; e < 8; e++) {
      u32 val = ((u32)(u16)r0[e]) | ((u32)(u16)r1[e] << 16);
      *(u32*)(wb + vwof[e]) = val;
    }
  };

  for (int half = 0; half < 2; half++) {
    const int qb = half ? pair : 15 - pair;
    const int qw = qb * 128 + wave * 32;
    const int nkt = 2 * qb + 2;  // even

    bf16x8 aq[2][2];
#pragma unroll
    for (int mi = 0; mi < 2; mi++)
#pragma unroll
      for (int kb = 0; kb < 2; kb++)
        aq[mi][kb] = *(const bf16x8*)(Q + base + (size_t)(qw + mi * 16 + col) * D + kb * 32 + quad * 8);

    f32x4 ao[2][4], lacc[2];
#pragma unroll
    for (int mi = 0; mi < 2; mi++) {
      lacc[mi] = (f32x4){0.f, 0.f, 0.f, 0.f};
#pragma unroll
      for (int dg = 0; dg < 4; dg++) ao[mi][dg] = (f32x4){0.f, 0.f, 0.f, 0.f};
    }

    // compute body for one k-tile; BF is compile-time per unrolled body
    auto compute = [&](const int BF, int kt) {
      const u16* kbK = kbase[BF];
      bf16x8 bk0[4], bk1[4];
#pragma unroll
      for (int n16 = 0; n16 < 4; n16++) {
        bk0[n16] = *(const bf16x8*)(kbK + n16 * 512);
        bk1[n16] = *(const bf16x8*)(kbK + n16 * 512 + 2048);
      }
      f32x4 sacc[2][4];
#pragma unroll
      for (int qi = 0; qi < 2; qi++)
#pragma unroll
        for (int n16 = 0; n16 < 4; n16++) sacc[qi][n16] = (f32x4){0.f, 0.f, 0.f, 0.f};
      __builtin_amdgcn_s_setprio(1);
#pragma unroll
      for (int qi = 0; qi < 2; qi++)
#pragma unroll
        for (int n16 = 0; n16 < 4; n16++) {
          sacc[qi][n16] = __builtin_amdgcn_mfma_f32_16x16x32_bf16(bk0[n16], aq[qi][0], sacc[qi][n16], 0, 0, 0);
          sacc[qi][n16] = __builtin_amdgcn_mfma_f32_16x16x32_bf16(bk1[n16], aq[qi][1], sacc[qi][n16], 0, 0, 0);
        }
      __builtin_amdgcn_s_setprio(0);
      const bool full = (kt * 64 + 63) <= qw;  // wave-uniform: no masking
#pragma unroll
      for (int qi = 0; qi < 2; qi++) {
        const int qg = qw + qi * 16 + col;
#pragma unroll
        for (int n16 = 0; n16 < 4; n16++) {
          float p0 = EXP2F(sacc[qi][n16][0]);
          float p1 = EXP2F(sacc[qi][n16][1]);
          float p2 = EXP2F(sacc[qi][n16][2]);
          float p3 = EXP2F(sacc[qi][n16][3]);
          if (!full) {
            int kg = kt * 64 + n16 * 16 + quad * 4;
            p0 = (kg + 0 > qg) ? 0.f : p0;
            p1 = (kg + 1 > qg) ? 0.f : p1;
            p2 = (kg + 2 > qg) ? 0.f : p2;
            p3 = (kg + 3 > qg) ? 0.f : p3;
          }
          u32 lo = cvt_pk_bf16(p0, p1);
          u32 hi = cvt_pk_bf16(p2, p3);
          *(u32x2*)(pww[qi] + swof[n16]) = (u32x2){lo, hi};
        }
      }
      // PV + ones-MFMA row sums (same-wave LDS write->read, in-order DS)
      const u16* vtB = vbase[BF];
      bf16x8 bv0[4], bv1[4];
#pragma unroll
      for (int dg = 0; dg < 4; dg++) {
        bv0[dg] = *(const bf16x8*)(vtB + dg * 1024 + vsl0);
        bv1[dg] = *(const bf16x8*)(vtB + dg * 1024 + vsl1);
      }
#pragma unroll
      for (int mi = 0; mi < 2; mi++) {
        bf16x8 ap0 = *(const bf16x8*)(apbase[mi] + vsl0);
        bf16x8 ap1 = *(const bf16x8*)(apbase[mi] + vsl1);
        __builtin_amdgcn_s_setprio(1);
#pragma unroll
        for (int dg = 0; dg < 4; dg++) {
          ao[mi][dg] = __builtin_amdgcn_mfma_f32_16x16x32_bf16(ap0, bv0[dg], ao[mi][dg], 0, 0, 0);
          ao[mi][dg] = __builtin_amdgcn_mfma_f32_16x16x32_bf16(ap1, bv1[dg], ao[mi][dg], 0, 0, 0);
        }
        lacc[mi] = __builtin_amdgcn_mfma_f32_16x16x32_bf16(ap0, bones, lacc[mi], 0, 0, 0);
        lacc[mi] = __builtin_amdgcn_mfma_f32_16x16x32_bf16(ap1, bones, lacc[mi], 0, 0, 0);
        __builtin_amdgcn_s_setprio(0);
      }
    };

    // ---- prologue ----
    bf16x8 vA0, vA1, vB0, vB1;
    const u16* gv = V + base + (size_t)vk0 * D + vdg * 8;  // V tile 0
    vA0 = *(const bf16x8*)gv;
    vA1 = *(const bf16x8*)(gv + D);
    __syncthreads();  // previous half's LDS readers done before restaging
    const u16* gk = K + base + (size_t)kk * D + dch * 8;   // K tile 0
    gld_lds16(gk, dk[0][0]);
    gld_lds16(gk + 32, dk[0][1]);
    gk += (size_t)64 * D;  // -> tile 1
    vstage(0, vA0, vA1);
    vB0 = *(const bf16x8*)(gv + (size_t)64 * D);           // V tile 1
    vB1 = *(const bf16x8*)(gv + (size_t)64 * D + D);
    gv += (size_t)128 * D;  // -> tile 2

    // ---- main loop, unrolled by 2 (bf = 0 then 1, compile-time) ----
    for (int kt = 0; kt < nkt; kt += 2) {
      // even body: bf=0, stage tile kt+1 -> buf1 from vB, load vA = tile kt+2
      __syncthreads();  // drains K(kt) DMA; publishes Vt[0]
      {
        // kt+1 < nkt always (nkt even)
        gld_lds16(gk, dk[1][0]);
        gld_lds16(gk + 32, dk[1][1]);
        gk += (size_t)64 * D;
        vstage(1, vB0, vB1);
        if (kt + 2 < nkt) {
          vA0 = *(const bf16x8*)gv;
          vA1 = *(const bf16x8*)(gv + D);
          gv += (size_t)64 * D;
        }
        if (kt * 64 <= qw + 31) compute(0, kt);
      }
      // odd body: bf=1, stage tile kt+2 -> buf0 from vA, load vB = tile kt+3
      __syncthreads();  // drains K(kt+1) DMA; publishes Vt[1]
      {
        const int kt1 = kt + 1;
        if (kt1 + 1 < nkt) {
          gld_lds16(gk, dk[0][0]);
          gld_lds16(gk + 32, dk[0][1]);
          gk += (size_t)64 * D;
          vstage(0, vA0, vA1);
          if (kt1 + 2 < nkt) {
            vB0 = *(const bf16x8*)gv;
            vB1 = *(const bf16x8*)(gv + D);
            gv += (size_t)64 * D;
          }
        }
        if (kt1 * 64 <= qw + 31) compute(1, kt1);
      }
    }
    // epilogue: normalize + write O
#pragma unroll
    for (int mi = 0; mi < 2; mi++)
#pragma unroll
      for (int r = 0; r < 4; r++) {
        float inv = 1.f / lacc[mi][r];
        int q = qw + mi * 16 + quad * 4 + r;
#pragma unroll
        for (int dg = 0; dg < 4; dg++)
          O[base + (size_t)q * D + dg * 16 + col] = f2bf(ao[mi][dg][r] * inv);
      }
  }
}

extern "C" void kernel_launch(void* const* d_in, const int* in_sizes, int n_in,
                              void* d_out, int out_size, void* d_ws, size_t ws_size,
                              hipStream_t stream) {
  const float* x  = (const float*)d_in[0];
  const float* Wq = (const float*)d_in[1];
  const float* Wk = (const float*)d_in[2];
  const float* Wv = (const float*)d_in[3];
  const float* Wo = (const float*)d_in[4];

  u16* xb  = (u16*)d_ws;
  u16* wqb = xb + (size_t)M * D;
  u16* wkb = wqb + (size_t)D * D;
  u16* wvb = wkb + (size_t)D * D;
  u16* wob = wvb + (size_t)D * D;
  u16* Qb  = wob + (size_t)D * D;
  u16* Kb  = Qb + (size_t)M * D;
  u16* Vb  = Kb + (size_t)M * D;
  u16* Ab  = xb;  // x dead after projections

  CastAll ca;
  ca.s[0] = Wq; ca.s[1] = Wk; ca.s[2] = Wv; ca.s[3] = Wo; ca.s[4] = x;
  ca.d[0] = wqb; ca.d[1] = wkb; ca.d[2] = wvb; ca.d[3] = wob; ca.d[4] = xb;
  ca.sc[0] = 0.18033688011112042f;  // 0.125 * log2(e) folded into Wq
  ca.sc[1] = 1.f; ca.sc[2] = 1.f; ca.sc[3] = 1.f; ca.sc[4] = 1.f;
  cast_all_kernel<<<4096 + M * D / 1024, 256, 0, stream>>>(ca);

  QkvArgs qa;
  qa.bt[0] = wqb; qa.bt[1] = wkb; qa.bt[2] = wvb;
  qa.c[0] = Qb; qa.c[1] = Kb; qa.c[2] = Vb;
  gemm_qkv<<<dim3(24, M / 256), 512, 0, stream>>>(xb, qa);

  attn_kernel<<<dim3(Bb * H, 8), 256, 0, stream>>>(Qb, Kb, Vb, Ab);

  gemm_f32<<<dim3(D / 128, M / 256), 512, 0, stream>>>(Ab, wob, (float*)d_out);
}